// Round 14
// baseline (1934.872 us; speedup 1.0000x reference)
//
#include <hip/hip_runtime.h>

#define TT   64
#define NB   8
#define NN   512
#define HID  128
#define G4   512
#define EE   8192
#define SBLK 16
#define NTHR 768

#define LOG2E 1.44269504088896f

// fast gates: v_exp2/v_rcp based, saturation-safe (rcp(inf)=0)
__device__ __forceinline__ float fsig(float x){
  return __builtin_amdgcn_rcpf(1.0f + __builtin_amdgcn_exp2f(-x*LOG2E));
}
__device__ __forceinline__ float ftanh(float x){
  return 1.0f - 2.0f*__builtin_amdgcn_rcpf(__builtin_amdgcn_exp2f(2.0f*LOG2E*x) + 1.0f);
}

using half8 = __attribute__((ext_vector_type(8))) _Float16;
using f32x4 = __attribute__((ext_vector_type(4))) float;

// ---------------------------------------------------------------------------
// Weight prep (layout verified R5..R13): f32 [512][128] x5 -> fp16 planes in
// MFMA B-fragment order. Matrix m occupies 65536 fp16 (128KB):
//   [kt(4)][half(2)][nl(16)][lane(64)][8 fp16]
// lane l elem j <-> W[n=(half*16+nl)*16+(l&15)][k=kt*32+8*(l>>4)+j]
// mats: 0=whh0 1=wih1 2=whh1 3=wih2 4=whh2
// ---------------------------------------------------------------------------
__global__ void prep_w(const float* __restrict__ whh0, const float* __restrict__ wih1,
                       const float* __restrict__ whh1, const float* __restrict__ wih2,
                       const float* __restrict__ whh2, _Float16* __restrict__ wp)
{
  int idx = blockIdx.x*256 + threadIdx.x;      // 5*512*128 total
  int mat = idx >> 16;
  int r   = (idx >> 7) & 511;
  int k   = idx & 127;
  const float* src = (mat==0)?whh0:(mat==1)?wih1:(mat==2)?whh1:(mat==3)?wih2:whh2;
  float v = src[r*HID + k];
  int kt = k >> 5, kk = k & 31, s0 = kk >> 3, j = kk & 7;
  int nt = r >> 4, half = nt >> 4, nl = nt & 15;
  int l  = (r & 15) + 16*s0;
  wp[(mat*8 + kt*2 + half)*8192 + nl*512 + l*8 + j] = (_Float16)v;
}

// ---------------------------------------------------------------------------
// R14: layer-pipelined LSTM scan. 256 blocks x 768 thr (12 waves).
// Wave w: layer L = w>>2, quarter q = w&3, unit-groups m = {2q, 2q+1}
// (units 16m..16m+15; the 4 gates of a unit land in one lane).
// Superstep s: layer L computes t = s-L (L0,L1,L2 concurrently in different
// waves -> MFMA and cell phases overlap across waves on each SIMD).
// h-state: hb[3 layers][2 parity][hi 4KB + lo 4KB] in LDS; layer writes h(t)
// to parity t&1. All same-superstep accesses are parity- or region-disjoint
// (verified pairwise) -> ONE barrier per superstep, 66 supersteps total.
// Inter-layer input = prev layer's hb (hi plane), read as A-fragments.
// Weights: B-fragments read per-superstep from the L2-hot 640KB wp pool
// (~9KB/CU/superstep; NOT pinned -> VGPR stays low, 3 waves/SIMD).
// ---------------------------------------------------------------------------
__global__ __launch_bounds__(NTHR,3) void lstm_scan(
    const float* __restrict__ x,    const float* __restrict__ wih0,
    const float* __restrict__ bih0, const float* __restrict__ bhh0,
    const float* __restrict__ bih1, const float* __restrict__ bhh1,
    const float* __restrict__ bih2, const float* __restrict__ bhh2,
    const _Float16* __restrict__ wp, float* __restrict__ feats)
{
  __shared__ __align__(16) _Float16 hb[3*2*4096];   // 48 KB h-state
  __shared__ __align__(16) _Float16 xall[TT*SBLK];  // 2 KB

  const int tid  = threadIdx.x;
  const int lane = tid & 63, wv = tid >> 6, row = lane & 15;
  const int L    = wv >> 2, q = wv & 3;
  const int s0   = blockIdx.x * SBLK;
  const int b    = s0 >> 9, n0 = s0 & (NN-1);
  char* hbB = (char*)hb;

  for (int i = tid; i < 3*2*4096; i += NTHR) hb[i] = (_Float16)0.0f;
  for (int i = tid; i < TT*SBLK; i += NTHR)
    xall[i] = (_Float16)x[(b*TT + (i>>4))*NN + n0 + (i&15)];

  // wave-uniform per-layer pointers
  const float* bihp = (L==0)?bih0:(L==1)?bih1:bih2;
  const float* bhhp = (L==0)?bhh0:(L==1)?bhh1:bhh2;
  const char*  whhG = (const char*)(wp + ((L==0)?0:(L==1)?2:4)*65536);
  const char*  wihG = (const char*)(wp + ((L==1)?1:3)*65536);   // used if L>0

  int un[2];  un[0] = 16*(2*q)   + row;  un[1] = 16*(2*q+1) + row;

  float bs[2][4], w0g[2][4];
  #pragma unroll
  for (int mi=0;mi<2;mi++)
    #pragma unroll
    for (int g=0;g<4;g++){
      bs[mi][g]  = bihp[g*HID+un[mi]] + bhhp[g*HID+un[mi]];
      w0g[mi][g] = (L==0) ? wih0[g*HID+un[mi]] : 0.0f;
    }

  // loop-invariant offsets
  int rboff[4], wby[2][4], boff[2][4][4];
  #pragma unroll
  for (int kt=0;kt<4;kt++)
    rboff[kt] = row*256 + (((kt<<6) + ((lane>>4)<<4)) ^ ((row&7)<<4));
  #pragma unroll
  for (int mi=0;mi<2;mi++)
    #pragma unroll
    for (int r=0;r<4;r++){
      int sq = 4*(lane>>4)+r;
      wby[mi][r] = sq*256 + ((un[mi]*2) ^ ((sq&7)<<4));
    }
  #pragma unroll
  for (int mi=0;mi<2;mi++)
    #pragma unroll
    for (int g=0;g<4;g++)
      #pragma unroll
      for (int kt=0;kt<4;kt++){
        int nt = g*8 + 2*q + mi;
        boff[mi][g][kt] = kt*32768 + (nt>>4)*16384 + (nt&15)*1024 + lane*16;
      }

  float cs[2][4] = {{0,0,0,0},{0,0,0,0}};
  __syncthreads();

  #pragma unroll 1
  for (int s = 0; s < TT+2; ++s){
    const int t = s - L;
    if (t >= 0 && t < TT){
      const int rb = (t+1)&1, wb = t&1;
      const char* hbR = hbB + L*16384 + rb*8192;

      f32x4 acc[2][4];
      #pragma unroll
      for (int mi=0;mi<2;mi++)
        #pragma unroll
        for (int g=0;g<4;g++)
          acc[mi][g] = (f32x4){bs[mi][g],bs[mi][g],bs[mi][g],bs[mi][g]};

      if (L>0){                          // input term: prev layer's h(t), hi
        const char* hbP = hbB + (L-1)*16384 + wb*8192;
        #pragma unroll
        for (int kt=0;kt<4;kt++){
          half8 pf = *(const half8*)(hbP + rboff[kt]);
          #pragma unroll
          for (int mi=0;mi<2;mi++)
            #pragma unroll
            for (int g=0;g<4;g++){
              half8 B = *(const half8*)(wihG + boff[mi][g][kt]);
              acc[mi][g] = __builtin_amdgcn_mfma_f32_16x16x32_f16(pf, B, acc[mi][g],0,0,0);
            }
        }
      }

      // recurrent term: own h(t-1) hi+lo
      #pragma unroll
      for (int kt=0;kt<4;kt++){
        half8 ahh = *(const half8*)(hbR + rboff[kt]);
        half8 ahl = *(const half8*)(hbR + 4096 + rboff[kt]);
        #pragma unroll
        for (int mi=0;mi<2;mi++)
          #pragma unroll
          for (int g=0;g<4;g++){
            half8 B = *(const half8*)(whhG + boff[mi][g][kt]);
            acc[mi][g] = __builtin_amdgcn_mfma_f32_16x16x32_f16(ahh, B, acc[mi][g],0,0,0);
            acc[mi][g] = __builtin_amdgcn_mfma_f32_16x16x32_f16(ahl, B, acc[mi][g],0,0,0);
          }
      }

      char* hbW = hbB + L*16384 + wb*8192;
      #pragma unroll
      for (int mi=0;mi<2;mi++)
        #pragma unroll
        for (int r=0;r<4;r++){
          float iv=acc[mi][0][r], fv=acc[mi][1][r], gv=acc[mi][2][r], ov=acc[mi][3][r];
          if (L==0){
            float xv = (float)xall[t*SBLK + 4*(lane>>4)+r];
            iv+=xv*w0g[mi][0]; fv+=xv*w0g[mi][1]; gv+=xv*w0g[mi][2]; ov+=xv*w0g[mi][3];
          }
          float cn = fsig(fv)*cs[mi][r] + fsig(iv)*ftanh(gv);
          cs[mi][r]=cn; float hn = fsig(ov)*ftanh(cn);
          _Float16 hh = (_Float16)hn;
          _Float16 hl = (_Float16)(hn - (float)hh);
          *(_Float16*)(hbW + wby[mi][r])        = hh;
          *(_Float16*)(hbW + 4096 + wby[mi][r]) = hl;
          if (L==2 && t==TT-1)
            feats[(s0 + 4*(lane>>4) + r)*HID + un[mi]] = hn;
        }
    }
    __syncthreads();                     // single barrier per superstep
  }
}

// ---------------------------------------------------------------------------
// GCN part (unchanged from verified baseline)
// ---------------------------------------------------------------------------
template<int KOUT>
__global__ void gcn_gemm(const float* __restrict__ in, const float* __restrict__ W,
                         const float* __restrict__ pre_bias, float* __restrict__ out)
{
  int id  = blockIdx.x*256 + threadIdx.x;
  int row = id / KOUT;
  int o   = id & (KOUT-1);
  const float4* a4 = (const float4*)(in + row*HID);
  const float4* w4 = (const float4*)(W + o*HID);
  float acc = 0.f;
  if (pre_bias){
    const float4* b4 = (const float4*)pre_bias;
    #pragma unroll 8
    for (int k=0;k<HID/4;k++){
      float4 av=a4[k], wv=w4[k], bv=b4[k];
      acc += fmaxf(av.x+bv.x,0.f)*wv.x + fmaxf(av.y+bv.y,0.f)*wv.y
           + fmaxf(av.z+bv.z,0.f)*wv.z + fmaxf(av.w+bv.w,0.f)*wv.w;
    }
  } else {
    #pragma unroll 8
    for (int k=0;k<HID/4;k++){
      float4 av=a4[k], wv=w4[k];
      acc += av.x*wv.x + av.y*wv.y + av.z*wv.z + av.w*wv.w;
    }
  }
  out[id] = acc;
}

__global__ void deg_init(float* deg){
  int i = blockIdx.x*256 + threadIdx.x;
  if (i < NN) deg[i] = 1.0f;             // self-loop
}
__global__ void deg_edges(const int* __restrict__ ei, float* deg){
  int e = blockIdx.x*256 + threadIdx.x;
  if (e < EE) atomicAdd(&deg[ei[EE+e]], 1.0f);
}
__global__ void build_A(const int* __restrict__ ei, const float* __restrict__ deg,
                        float* __restrict__ A){
  int e = blockIdx.x*256 + threadIdx.x;
  if (e < EE){
    int s = ei[e], d = ei[EE+e];
    atomicAdd(&A[d*NN+s], rsqrtf(deg[s])*rsqrtf(deg[d]));
  } else if (e < EE+NN){
    int n = e - EE;
    atomicAdd(&A[n*NN+n], 1.0f/deg[n]);
  }
}

template<int KOUT>
__global__ __launch_bounds__(512) void gcn_agg(const float* __restrict__ A,
    const float* __restrict__ X, float* __restrict__ Y)
{
  const int F4 = KOUT/4;
  const int TN = 16;
  __shared__ __align__(16) float As[TN*NN];
  const int b = blockIdx.x, n0 = blockIdx.y*TN;
  const int tid = threadIdx.x;
  const int f4 = tid & (F4-1), nr = tid / F4;
  for (int i = tid; i < TN*NN; i += TN*F4) As[i] = A[n0*NN + i];
  __syncthreads();
  const float* Xb = X + b*NN*KOUT + f4*4;
  const float* Ar = As + nr*NN;
  float4 s = {0,0,0,0};
  #pragma unroll 4
  for (int m=0;m<NN;m++){
    float a = Ar[m];
    float4 xv = *(const float4*)(Xb + m*KOUT);
    s.x += a*xv.x; s.y += a*xv.y; s.z += a*xv.z; s.w += a*xv.w;
  }
  *(float4*)(Y + (b*NN + n0 + nr)*KOUT + f4*4) = s;
}

__global__ void finalize(const float* __restrict__ agg2, const float* __restrict__ b2,
                         const float* __restrict__ clw, const float* __restrict__ clb,
                         float* __restrict__ out)
{
  __shared__ float red[256];
  int bb = blockIdx.x, tid = threadIdx.x;
  float acc = 0.f;
  for (int i = tid; i < NN*64; i += 256){
    int j = i & 63;
    float v = agg2[bb*NN*64 + i] + b2[j];
    acc += fmaxf(v, 0.f) * clw[j];
  }
  red[tid] = acc; __syncthreads();
  for (int sfd=128; sfd>0; sfd>>=1){
    if (tid < sfd) red[tid] += red[tid+sfd];
    __syncthreads();
  }
  if (tid==0) out[bb] = red[0]*(1.0f/NN) + clb[0];
}

extern "C" void kernel_launch(void* const* d_in, const int* in_sizes, int n_in,
                              void* d_out, int out_size, void* d_ws, size_t ws_size,
                              hipStream_t stream)
{
  const float* x    = (const float*)d_in[0];
  const int*   ei   = (const int*)  d_in[1];
  const float* wih0 = (const float*)d_in[2];
  const float* whh0 = (const float*)d_in[3];
  const float* bih0 = (const float*)d_in[4];
  const float* bhh0 = (const float*)d_in[5];
  const float* wih1 = (const float*)d_in[6];
  const float* whh1 = (const float*)d_in[7];
  const float* bih1 = (const float*)d_in[8];
  const float* bhh1 = (const float*)d_in[9];
  const float* wih2 = (const float*)d_in[10];
  const float* whh2 = (const float*)d_in[11];
  const float* bih2 = (const float*)d_in[12];
  const float* bhh2 = (const float*)d_in[13];
  const float* g1w  = (const float*)d_in[14];
  const float* g1b  = (const float*)d_in[15];
  const float* g2w  = (const float*)d_in[16];
  const float* g2b  = (const float*)d_in[17];
  const float* clw  = (const float*)d_in[18];
  const float* clb  = (const float*)d_in[19];
  float* out = (float*)d_out;

  char* ws = (char*)d_ws;
  float* feats = (float*)(ws);                 // [4096,128]  2 MB
  float* xl1   = (float*)(ws + 2097152);       // [8,512,128] 2 MB (post-lstm)
  float* agg1  = (float*)(ws + 4194304);       // [8,512,128] 2 MB (post-lstm)
  float* xl2   = (float*)(ws + 6291456);       // [8,512,64]  1 MB (post-lstm)
  float* agg2  = (float*)(ws + 7340032);       // [8,512,64]  1 MB (post-lstm)
  float* A     = (float*)(ws + 8388608);       // [512,512]   1 MB
  float* deg   = (float*)(ws + 9437184);       // [512]

  // wp (640KB fp16 weight planes) overlays the xl2 slot: consumed by
  // lstm_scan strictly before gcn_gemm<64> writes xl2 (stream order).
  _Float16* wpW = (_Float16*)(ws + 6291456);

  prep_w<<<(5*G4*HID)/256, 256, 0, stream>>>(whh0, wih1, whh1, wih2, whh2, wpW);

  hipMemsetAsync(A, 0, NN*NN*sizeof(float), stream);
  deg_init <<<2, 256, 0, stream>>>(deg);
  deg_edges<<<EE/256, 256, 0, stream>>>(ei, deg);
  build_A  <<<(EE+NN+255)/256, 256, 0, stream>>>(ei, deg, A);

  lstm_scan<<<256, NTHR, 0, stream>>>(x, wih0, bih0, bhh0,
      bih1, bhh1, bih2, bhh2, wpW, feats);

  gcn_gemm<128><<<(4096*128)/256, 256, 0, stream>>>(feats, g1w, nullptr, xl1);
  gcn_agg<128><<<dim3(NB, NN/16), 512, 0, stream>>>(A, xl1, agg1);
  gcn_gemm<64><<<(4096*64)/256, 256, 0, stream>>>(agg1, g2w, g1b, xl2);
  gcn_agg<64><<<dim3(NB, NN/16), 256, 0, stream>>>(A, xl2, agg2);
  finalize<<<NB, 256, 0, stream>>>(agg2, g2b, clw, clb, out);
}

// Round 16
// 574.280 us; speedup vs baseline: 3.3692x; 3.3692x over previous
//
#include <hip/hip_runtime.h>

#define TT   64
#define NB   8
#define NN   512
#define HID  128
#define G4   512
#define EE   8192
#define SBLK 16
#define NTHR 512
#define TCH  32
#define NCH  2

#define LOG2E 1.44269504088896f

// fast gates: v_exp2/v_rcp based, saturation-safe (rcp(inf)=0)
__device__ __forceinline__ float fsig(float x){
  return __builtin_amdgcn_rcpf(1.0f + __builtin_amdgcn_exp2f(-x*LOG2E));
}
__device__ __forceinline__ float ftanh(float x){
  return 1.0f - 2.0f*__builtin_amdgcn_rcpf(__builtin_amdgcn_exp2f(2.0f*LOG2E*x) + 1.0f);
}

using half8 = __attribute__((ext_vector_type(8))) _Float16;
using f32x4 = __attribute__((ext_vector_type(4))) float;

// pin a 4-VGPR value: compiler may not rematerialize/DCE it (R7/R14 remat guard)
__device__ __forceinline__ void keepv(half8& v){
  asm volatile("" : "+v"(*(f32x4*)&v));
}

// ---------------------------------------------------------------------------
// Weight prep (layout verified R5..R13): f32 [512][128] x5 -> fp16 planes in
// MFMA B-fragment order. Matrix m occupies 65536 fp16 (128KB):
//   [kt(4)][half(2)][nl(16)][lane(64)][8 fp16]
// lane l elem j <-> W[n=(half*16+nl)*16+(l&15)][k=kt*32+8*(l>>4)+j]
// mats: 0=whh0 1=wih1 2=whh1 3=wih2 4=whh2
// ---------------------------------------------------------------------------
__global__ void prep_w(const float* __restrict__ whh0, const float* __restrict__ wih1,
                       const float* __restrict__ whh1, const float* __restrict__ wih2,
                       const float* __restrict__ whh2, _Float16* __restrict__ wp)
{
  int idx = blockIdx.x*256 + threadIdx.x;      // 5*512*128 total
  int mat = idx >> 16;
  int r   = (idx >> 7) & 511;
  int k   = idx & 127;
  const float* src = (mat==0)?whh0:(mat==1)?wih1:(mat==2)?whh1:(mat==3)?wih2:whh2;
  float v = src[r*HID + k];
  int kt = k >> 5, kk = k & 31, s0 = kk >> 3, j = kk & 7;
  int nt = r >> 4, half = nt >> 4, nl = nt & 15;
  int l  = (r & 15) + 16*s0;
  wp[(mat*8 + kt*2 + half)*8192 + nl*512 + l*8 + j] = (_Float16)v;
}

// ---------------------------------------------------------------------------
// One layer-phase over [ch*TCH, ch*TCH+TCH). R15 = R13 structure with
// SINGLE-fp16 recurrent h (lo-plane dropped): recurrent MFMA halved,
// A-fragment LDS reads halved, cell drops the hl cvt+store.
//  - whh/wih B-fragments: global -> pinned regs, once per phase (R13-verified)
//  - inter-layer h: LDS hseq ring [TCH][4KB] (hi-only, as before)
//  - recurrent h: ping-pong hb (2 x 4KB, hi only), 1 barrier/step
//  - steady-state loop has ZERO global memory ops
// ---------------------------------------------------------------------------
template<int L>
__device__ __forceinline__ void scan_phase(
    int ch, const _Float16* __restrict__ wp, _Float16* __restrict__ hsave,
    _Float16* hseq, _Float16* hb, const _Float16* xall,
    float4 bL, float4 w0g, float (&cs)[4], float (&hlast)[4])
{
  const int tid  = threadIdx.x;
  const int lane = tid & 63, wv = tid >> 6, row = lane & 15;
  const int u    = 16*wv + row;
  const int blk  = blockIdx.x;

  __syncthreads();                     // phase entry: prev phase's hseq/hb done

  // ---- whh B-fragments: global -> pinned regs (L2-hot 640KB pool)
  const char* whhG = (const char*)(wp + (L==0?0:(L==1?2:4))*65536);
  half8 Wf[4][4];
  #pragma unroll
  for (int g=0;g<4;g++)
    #pragma unroll
    for (int kt=0;kt<4;kt++){
      Wf[g][kt] = *(const half8*)(whhG + kt*32768 + (g>>1)*16384
                                  + (wv+8*(g&1))*1024 + lane*16);
      keepv(Wf[g][kt]);
    }
  // ---- wih B-fragments (L>0): global -> pinned regs
  half8 wih[4][4];
  if (L>0){
    const char* wihG = (const char*)(wp + (L==1?1:3)*65536);
    #pragma unroll
    for (int g=0;g<4;g++)
      #pragma unroll
      for (int kt=0;kt<4;kt++){
        wih[g][kt] = *(const half8*)(wihG + kt*32768 + (g>>1)*16384
                                     + (wv+8*(g&1))*1024 + lane*16);
        keepv(wih[g][kt]);
      }
  }

  // ---- init recurrent h-state (buf0, 4KB): zero (ch0) or restore (ch1)
  if (ch == 0){
    for (int i=tid;i<2048;i+=NTHR) hb[i] = (_Float16)0.0f;
  } else {
    const unsigned long long* s =
      (const unsigned long long*)(hsave + (size_t)(L*256+blk)*4096);
    ((unsigned long long*)hb)[tid] = s[tid];                      // 4KB restore
  }

  // ---- loop-invariant offsets
  int rboff[4], wbyteW[4], stoffW[4];
  #pragma unroll
  for (int kt=0;kt<4;kt++)
    rboff[kt] = row*256 + (((kt<<6) + ((lane>>4)<<4)) ^ ((row&7)<<4));
  #pragma unroll
  for (int r=0;r<4;r++){
    int sq = 4*(lane>>4)+r;
    wbyteW[r] = sq*256 + ((u*2) ^ ((sq&7)<<4));
    stoffW[r] = (wv>>1)*512 + (2*(wv&1)+((lane&15)>>3))*128 + sq*8 + (lane&7);
  }

  __syncthreads();                     // hb init visible

  const char* hseq_c = (const char*)hseq;
  half8 pfA[4];
  if (L>0){                            // prefetch tile 0 (prev-layer h)
    #pragma unroll
    for (int kt=0;kt<4;kt++)
      pfA[kt] = *(const half8*)(hseq_c + kt*1024 + lane*16);
  }

  #pragma unroll 1
  for (int tt=0; tt<TCH; ++tt){
    const int t = ch*TCH + tt;
    __syncthreads();                   // single barrier per step (lgkm-only)

    f32x4 acc[4];
    #pragma unroll
    for (int g=0;g<4;g++) acc[g] = (f32x4){bL[g],bL[g],bL[g],bL[g]};

    if (L>0){                          // input-projection term (prev-layer h)
      #pragma unroll
      for (int g=0;g<4;g++)
        #pragma unroll
        for (int kt=0;kt<4;kt++)
          acc[g] = __builtin_amdgcn_mfma_f32_16x16x32_f16(pfA[kt], wih[g][kt], acc[g],0,0,0);
    }

    // recurrent term: A = h(t-1) fp16 from hb[tt&1], B = whh (pinned regs)
    const char* hbR = (const char*)hb + (tt&1)*4096;
    half8 ahh[4];
    #pragma unroll
    for (int kt=0;kt<4;kt++)
      ahh[kt] = *(const half8*)(hbR + rboff[kt]);
    #pragma unroll
    for (int g=0;g<4;g++)
      #pragma unroll
      for (int kt=0;kt<4;kt++)
        acc[g] = __builtin_amdgcn_mfma_f32_16x16x32_f16(ahh[kt], Wf[g][kt], acc[g],0,0,0);

    if (L>0 && tt+1 < TCH){            // prefetch hseq[tt+1] (safe: its next
      #pragma unroll                   // writer runs after the NEXT barrier)
      for (int kt=0;kt<4;kt++)
        pfA[kt] = *(const half8*)(hseq_c + (tt+1)*4096 + kt*1024 + lane*16);
    }

    char* hbW = (char*)hb + ((tt+1)&1)*4096;
    _Float16* sq16 = hseq + tt*2048;   // this step's hseq tile (overwrite ok:
    #pragma unroll                     // all pfA[tt] reads were pre-barrier)
    for (int r=0;r<4;r++){
      float iv=acc[0][r], fv=acc[1][r], gv=acc[2][r], ov=acc[3][r];
      if (L==0){
        float xv = (float)xall[t*SBLK + 4*(lane>>4)+r];
        iv+=xv*w0g[0]; fv+=xv*w0g[1]; gv+=xv*w0g[2]; ov+=xv*w0g[3];
      }
      float cn = fsig(fv)*cs[r] + fsig(iv)*ftanh(gv);
      cs[r]=cn; float hn = fsig(ov)*ftanh(cn);
      _Float16 hh = (_Float16)hn;
      *(_Float16*)(hbW + wbyteW[r]) = hh;
      if (L<2) sq16[stoffW[r]] = hh;   // fragment-ordered hseq write
      if (L==2 && t==TT-1) hlast[r]=hn;
    }
  }

  __syncthreads();                     // final writes visible
  if (NCH>1 && ch==0){                 // save 4KB h-state for next chunk
    // hsave entry STRIDE stays 8KB (R13 layout): feats/hsave overlay is
    // then self-block-aliased only (block i's feats region == hsave[0][i]).
    unsigned long long* d =
      (unsigned long long*)(hsave + (size_t)(L*256+blk)*4096);
    d[tid] = ((const unsigned long long*)((const char*)hb + (TCH&1)*4096))[tid];
  }
}

// ---------------------------------------------------------------------------
// Fused 3-layer LSTM scan: layer-sequential, weights in pinned regs,
// inter-layer h in LDS hseq ring, single-fp16 h, 1 barrier/step.
// 256 blocks x 512 thr; 16 seqs/block x 3 layers x 64 steps (2 chunks of 32).
// LDS: 128K hseq + 8K hb(pp) + 2K xall = 138K.
// ---------------------------------------------------------------------------
__global__ __launch_bounds__(NTHR,2) void lstm_scan(
    const float* __restrict__ x,    const float* __restrict__ wih0,
    const float* __restrict__ bih0, const float* __restrict__ bhh0,
    const float* __restrict__ bih1, const float* __restrict__ bhh1,
    const float* __restrict__ bih2, const float* __restrict__ bhh2,
    const _Float16* __restrict__ wp, _Float16* __restrict__ hsave,
    float* __restrict__ feats)
{
  __shared__ __align__(16) _Float16 hseq[TCH*2048];  // 128 KB inter-layer h ring
  __shared__ __align__(16) _Float16 hb[2*2048];      // 8 KB ping-pong h (fp16)
  __shared__ __align__(16) _Float16 xall[TT*SBLK];   // 2 KB

  const int tid  = threadIdx.x;
  const int lane = tid & 63, wv = tid >> 6;
  const int u    = 16*wv + (lane & 15);
  const int s0   = blockIdx.x * SBLK;
  const int b    = s0 >> 9, n0 = s0 & (NN-1);

  for (int i = tid; i < TT*SBLK; i += NTHR)
    xall[i] = (_Float16)x[(b*TT + (i>>4))*NN + n0 + (i&15)];

  float4 b0, b1, b2, w0g;
  #pragma unroll
  for (int g=0; g<4; g++){
    b0[g]  = bih0[g*HID+u] + bhh0[g*HID+u];
    b1[g]  = bih1[g*HID+u] + bhh1[g*HID+u];
    b2[g]  = bih2[g*HID+u] + bhh2[g*HID+u];
    w0g[g] = wih0[g*HID+u];
  }

  float cs0[4]={0,0,0,0}, cs1[4]={0,0,0,0}, cs2[4]={0,0,0,0};
  float hlast[4]={0,0,0,0};

  #pragma unroll 1
  for (int ch=0; ch<NCH; ++ch){
    scan_phase<0>(ch, wp, hsave, hseq, hb, xall, b0, w0g, cs0, hlast);
    scan_phase<1>(ch, wp, hsave, hseq, hb, xall, b1, w0g, cs1, hlast);
    scan_phase<2>(ch, wp, hsave, hseq, hb, xall, b2, w0g, cs2, hlast);
  }

  #pragma unroll
  for (int r=0;r<4;r++)
    feats[(s0 + 4*(lane>>4) + r)*HID + u] = hlast[r];
}

// ---------------------------------------------------------------------------
// GCN part (unchanged from verified baseline)
// ---------------------------------------------------------------------------
template<int KOUT>
__global__ void gcn_gemm(const float* __restrict__ in, const float* __restrict__ W,
                         const float* __restrict__ pre_bias, float* __restrict__ out)
{
  int id  = blockIdx.x*256 + threadIdx.x;
  int row = id / KOUT;
  int o   = id & (KOUT-1);
  const float4* a4 = (const float4*)(in + row*HID);
  const float4* w4 = (const float4*)(W + o*HID);
  float acc = 0.f;
  if (pre_bias){
    const float4* b4 = (const float4*)pre_bias;
    #pragma unroll 8
    for (int k=0;k<HID/4;k++){
      float4 av=a4[k], wv=w4[k], bv=b4[k];
      acc += fmaxf(av.x+bv.x,0.f)*wv.x + fmaxf(av.y+bv.y,0.f)*wv.y
           + fmaxf(av.z+bv.z,0.f)*wv.z + fmaxf(av.w+bv.w,0.f)*wv.w;
    }
  } else {
    #pragma unroll 8
    for (int k=0;k<HID/4;k++){
      float4 av=a4[k], wv=w4[k];
      acc += av.x*wv.x + av.y*wv.y + av.z*wv.z + av.w*wv.w;
    }
  }
  out[id] = acc;
}

__global__ void deg_init(float* deg){
  int i = blockIdx.x*256 + threadIdx.x;
  if (i < NN) deg[i] = 1.0f;             // self-loop
}
__global__ void deg_edges(const int* __restrict__ ei, float* deg){
  int e = blockIdx.x*256 + threadIdx.x;
  if (e < EE) atomicAdd(&deg[ei[EE+e]], 1.0f);
}
__global__ void build_A(const int* __restrict__ ei, const float* __restrict__ deg,
                        float* __restrict__ A){
  int e = blockIdx.x*256 + threadIdx.x;
  if (e < EE){
    int s = ei[e], d = ei[EE+e];
    atomicAdd(&A[d*NN+s], rsqrtf(deg[s])*rsqrtf(deg[d]));
  } else if (e < EE+NN){
    int n = e - EE;
    atomicAdd(&A[n*NN+n], 1.0f/deg[n]);
  }
}

template<int KOUT>
__global__ __launch_bounds__(512) void gcn_agg(const float* __restrict__ A,
    const float* __restrict__ X, float* __restrict__ Y)
{
  const int F4 = KOUT/4;
  const int TN = 16;
  __shared__ __align__(16) float As[TN*NN];
  const int b = blockIdx.x, n0 = blockIdx.y*TN;
  const int tid = threadIdx.x;
  const int f4 = tid & (F4-1), nr = tid / F4;
  for (int i = tid; i < TN*NN; i += TN*F4) As[i] = A[n0*NN + i];
  __syncthreads();
  const float* Xb = X + b*NN*KOUT + f4*4;
  const float* Ar = As + nr*NN;
  float4 s = {0,0,0,0};
  #pragma unroll 4
  for (int m=0;m<NN;m++){
    float a = Ar[m];
    float4 xv = *(const float4*)(Xb + m*KOUT);
    s.x += a*xv.x; s.y += a*xv.y; s.z += a*xv.z; s.w += a*xv.w;
  }
  *(float4*)(Y + (b*NN + n0 + nr)*KOUT + f4*4) = s;
}

__global__ void finalize(const float* __restrict__ agg2, const float* __restrict__ b2,
                         const float* __restrict__ clw, const float* __restrict__ clb,
                         float* __restrict__ out)
{
  __shared__ float red[256];
  int bb = blockIdx.x, tid = threadIdx.x;
  float acc = 0.f;
  for (int i = tid; i < NN*64; i += 256){
    int j = i & 63;
    float v = agg2[bb*NN*64 + i] + b2[j];
    acc += fmaxf(v, 0.f) * clw[j];
  }
  red[tid] = acc; __syncthreads();
  for (int sfd=128; sfd>0; sfd>>=1){
    if (tid < sfd) red[tid] += red[tid+sfd];
    __syncthreads();
  }
  if (tid==0) out[bb] = red[0]*(1.0f/NN) + clb[0];
}

extern "C" void kernel_launch(void* const* d_in, const int* in_sizes, int n_in,
                              void* d_out, int out_size, void* d_ws, size_t ws_size,
                              hipStream_t stream)
{
  const float* x    = (const float*)d_in[0];
  const int*   ei   = (const int*)  d_in[1];
  const float* wih0 = (const float*)d_in[2];
  const float* whh0 = (const float*)d_in[3];
  const float* bih0 = (const float*)d_in[4];
  const float* bhh0 = (const float*)d_in[5];
  const float* wih1 = (const float*)d_in[6];
  const float* whh1 = (const float*)d_in[7];
  const float* bih1 = (const float*)d_in[8];
  const float* bhh1 = (const float*)d_in[9];
  const float* wih2 = (const float*)d_in[10];
  const float* whh2 = (const float*)d_in[11];
  const float* bih2 = (const float*)d_in[12];
  const float* bhh2 = (const float*)d_in[13];
  const float* g1w  = (const float*)d_in[14];
  const float* g1b  = (const float*)d_in[15];
  const float* g2w  = (const float*)d_in[16];
  const float* g2b  = (const float*)d_in[17];
  const float* clw  = (const float*)d_in[18];
  const float* clb  = (const float*)d_in[19];
  float* out = (float*)d_out;

  char* ws = (char*)d_ws;
  float* feats = (float*)(ws);                 // [4096,128]  2 MB
  float* xl1   = (float*)(ws + 2097152);       // [8,512,128] 2 MB (post-lstm)
  float* agg1  = (float*)(ws + 4194304);       // [8,512,128] 2 MB (post-lstm)
  float* xl2   = (float*)(ws + 6291456);       // [8,512,64]  1 MB (post-lstm)
  float* agg2  = (float*)(ws + 7340032);       // [8,512,64]  1 MB (post-lstm)
  float* A     = (float*)(ws + 8388608);       // [512,512]   1 MB
  float* deg   = (float*)(ws + 9437184);       // [512]

  // Overlays (safe by stream order + R13-verified self-alias layout):
  //  - hsave [3][256] stride 8KB = 6MB at ws+0 (feats/xl1/agg1 dead during
  //    scan; block i's feats region == hsave[0][i], restored before written).
  //  - wp (640KB fp16 weight planes) in the xl2 slot.
  _Float16* hsaveW = (_Float16*)(ws);
  _Float16* wpW    = (_Float16*)(ws + 6291456);

  prep_w<<<(5*G4*HID)/256, 256, 0, stream>>>(whh0, wih1, whh1, wih2, whh2, wpW);

  hipMemsetAsync(A, 0, NN*NN*sizeof(float), stream);
  deg_init <<<2, 256, 0, stream>>>(deg);
  deg_edges<<<EE/256, 256, 0, stream>>>(ei, deg);
  build_A  <<<(EE+NN+255)/256, 256, 0, stream>>>(ei, deg, A);

  lstm_scan<<<256, NTHR, 0, stream>>>(x, wih0, bih0, bhh0,
      bih1, bhh1, bih2, bhh2, wpW, hsaveW, feats);

  gcn_gemm<128><<<(4096*128)/256, 256, 0, stream>>>(feats, g1w, nullptr, xl1);
  gcn_agg<128><<<dim3(NB, NN/16), 512, 0, stream>>>(A, xl1, agg1);
  gcn_gemm<64><<<(4096*64)/256, 256, 0, stream>>>(agg1, g2w, g1b, xl2);
  gcn_agg<64><<<dim3(NB, NN/16), 256, 0, stream>>>(A, xl2, agg2);
  finalize<<<NB, 256, 0, stream>>>(agg2, g2b, clw, clb, out);
}